// Round 8
// baseline (57.789 us; speedup 1.0000x reference)
//
#include <hip/hip_runtime.h>

#define DD    2048
#define KK    256
#define NS    256
#define BB    64
#define SPW   4              // samples per wave
#define WPB   4              // waves per block
#define SPB   (SPW * WPB)    // 16 samples per block
#define NG    (NS / SPB)     // 16 groups (blocks) per b
#define NBIN  256            // fine-window bins
#define WHALF 0.5f           // window half-width around tEst
#define FSCALE 256.0f        // NBIN / (2*WHALF)
#define CWAVE 32             // candidate slots per wave
#define PSEGW 17             // coarse hist: padded segment width
#define KK4   (4 * KK)       // coarse crossing target (4 waves duplicate x)

// Map float bits to order-preserving unsigned, and back.
__device__ __forceinline__ uint32_t orderable(float f) {
    uint32_t u = __float_as_uint(f);
    return (u & 0x80000000u) ? ~u : (u | 0x80000000u);
}
__device__ __forceinline__ float inv_orderable(uint32_t u) {
    return (u & 0x80000000u) ? __uint_as_float(u & 0x7FFFFFFFu)
                             : __uint_as_float(~u);
}

// ---- macros (explicit components / static indices: no scratch) ----
#define CRS1(Q, COMP)                                                   \
    { uint32_t bkt = orderable(xv[Q].COMP) >> 20;                       \
      atomicAdd(&coarse[(bkt >> 4) * PSEGW + (bkt & 15u)], 1u); }
#define CRS4(Q) CRS1(Q, x) CRS1(Q, y) CRS1(Q, z) CRS1(Q, w)

#define LOADN(V, S)                                                     \
    { const float4* nr = nbase + (size_t)(S) * (DD / 4);                \
      _Pragma("unroll")                                                 \
      for (int q = 0; q < 8; ++q) V[q] = nr[q * 64 + lane]; }

#define BIN1(V, Q, COMP)                                                \
    { float val = V[Q].COMP;                                            \
      if (val >= lo) {                                                  \
          int r = (int)((val - lo) * FSCALE);                           \
          if (r >= NBIN) ++W; else atomicAdd(&myHist[r], 1u);           \
      } }
#define BIN4(V, Q) BIN1(V, Q, x) BIN1(V, Q, y) BIN1(V, Q, z) BIN1(V, Q, w)

#define CLS1(V, Q, J, COMP)                                             \
    { float val = V[Q].COMP;                                            \
      if (val >= lo) {                                                  \
          int r = (int)((val - lo) * FSCALE);                           \
          if (r > tb) {                                                 \
              cnt##Q += (1u << (8 * (J)));   /* register byte ctr */    \
          } else if (r == tb) {                                         \
              uint32_t jj = atomicAdd(&candCnt[wid], 1u);               \
              if (jj < CWAVE) {                                         \
                  myCf[jj] = val;                                       \
                  myCd[jj] = (uint32_t)(((Q) << 8) + lane * 4 + (J));   \
              }                                                         \
          }                                                             \
      } }
#define CLS4(V, Q) CLS1(V, Q, 0, x) CLS1(V, Q, 1, y) CLS1(V, Q, 2, z) CLS1(V, Q, 3, w)

#define FLUSH1(Q, J)                                                    \
    { uint32_t byt = (cnt##Q >> (8 * (J))) & 0xFFu;                     \
      if (byt) atomicAdd(&counts[((Q) << 8) + lane * 4 + (J)], byt); }
#define FLUSH4(Q) FLUSH1(Q, 0) FLUSH1(Q, 1) FLUSH1(Q, 2) FLUSH1(Q, 3)

// One full per-sample pipeline stage on buffer V (perturb/bin/scan/classify).
#define DO_SAMPLE(V)                                                    \
    {                                                                   \
        _Pragma("unroll")                                               \
        for (int q = 0; q < 8; ++q) {                                   \
            V[q].x = fmaf(V[q].x, 0.05f, xv[q].x);                      \
            V[q].y = fmaf(V[q].y, 0.05f, xv[q].y);                      \
            V[q].z = fmaf(V[q].z, 0.05f, xv[q].z);                      \
            V[q].w = fmaf(V[q].w, 0.05f, xv[q].w);                      \
        }                                                               \
        uint32_t W = 0;                                                 \
        BIN4(V,0) BIN4(V,1) BIN4(V,2) BIN4(V,3)                         \
        BIN4(V,4) BIN4(V,5) BIN4(V,6) BIN4(V,7)                         \
        _Pragma("unroll")                                               \
        for (int st = 32; st >= 1; st >>= 1)                            \
            W += __shfl_down(W, (unsigned)st, 64);                      \
        W = __shfl(W, 0, 64);                                           \
        uint4 hh = *(const uint4*)&myHist[lane * 4];                    \
        const uint32_t h0 = hh.x, h1 = hh.y, h2 = hh.z, h3 = hh.w;      \
        uint32_t seg = h0 + h1 + h2 + h3;                               \
        uint32_t sfx = seg;                                             \
        _Pragma("unroll")                                               \
        for (int st = 1; st < 64; st <<= 1) {                           \
            uint32_t o = __shfl_down(sfx, (unsigned)st, 64);            \
            if (lane + st < 64) sfx += o;                               \
        }                                                               \
        const uint32_t incl  = sfx + W;                                 \
        const uint32_t above = incl - seg;                              \
        bool cross = (above < KK && incl >= KK);                        \
        unsigned long long mask = __ballot(cross);                      \
        int tbl = NBIN + 1; uint32_t Rl = 0;                            \
        if (cross) {                                                    \
            uint32_t c = above;                                         \
            if (c + h3 >= KK)                { tbl = lane*4+3; Rl = KK-c; } \
            else if (c + h3 + h2 >= KK)      { tbl = lane*4+2; Rl = KK-c-h3; } \
            else if (c + h3 + h2 + h1 >= KK) { tbl = lane*4+1; Rl = KK-c-h3-h2; } \
            else                             { tbl = lane*4+0; Rl = KK-c-h3-h2-h1; } \
        }                                                               \
        int srcl = mask ? (__ffsll((long long)mask) - 1) : 0;           \
        int      tb = __shfl(tbl, srcl, 64);                            \
        uint32_t R  = __shfl(Rl,  srcl, 64);                            \
        if (!mask) { tb = NBIN + 1; R = 0; }                            \
        CLS4(V,0) CLS4(V,1) CLS4(V,2) CLS4(V,3)                         \
        CLS4(V,4) CLS4(V,5) CLS4(V,6) CLS4(V,7)                         \
        uint32_t M = candCnt[wid];                                      \
        if (M > CWAVE) M = CWAVE;                                       \
        for (uint32_t j = lane; j < M; j += 64) {                       \
            float    vv = myCf[j];                                      \
            uint32_t dj = myCd[j];                                      \
            uint32_t r  = 0;                                            \
            for (uint32_t i = 0; i < M; ++i) {                          \
                float vi = myCf[i];                                     \
                r += (vi > vv) || (vi == vv && myCd[i] < dj);           \
            }                                                           \
            if (r < R) atomicAdd(&counts[dj], 1u);                      \
        }                                                               \
        if (lane == 0) candCnt[wid] = 0u;                               \
        *(uint4*)&myHist[lane * 4] = make_uint4(0u,0u,0u,0u);           \
    }

// Fused kernel: per-block coarse x-threshold + wave-per-sample fine window,
// 2-deep A/B load pipeline (latency-bound fix).
template <int USE_WS>
__global__ __launch_bounds__(256) void topk_fused_kernel(
    const float* __restrict__ x,
    const float* __restrict__ noise,
    unsigned char* __restrict__ ws,      // [BB][NG][DD] u8 partials
    float* __restrict__ outCounts)       // [BB][DD] f32 (fallback, pre-zeroed)
{
    const int tid  = threadIdx.x;
    const int bg   = blockIdx.x;
    const int b    = bg >> 4;            // / NG (NG=16)
    const int g    = bg & (NG - 1);
    const int lane = tid & 63;
    const int wid  = tid >> 6;

    __shared__ uint32_t counts[DD];            // 8 KB
    __shared__ uint32_t hist[WPB * NBIN];      // 4 KB, per-wave fine hist
    __shared__ uint32_t coarse[256 * PSEGW];   // 17 KB, block coarse hist
    __shared__ float    cand_f[WPB * CWAVE];
    __shared__ uint32_t cand_d[WPB * CWAVE];
    __shared__ uint32_t candCnt[WPB];
    __shared__ uint32_t wsum[4];
    __shared__ float    sh_lo;

    // ---- issue x loads + sample-0 loads immediately ----
    const float4* xr = (const float4*)(x + (size_t)b * DD);
    float4 xv[8];
    #pragma unroll
    for (int q = 0; q < 8; ++q) xv[q] = xr[q * 64 + lane];

    const int s0 = g * SPB + wid * SPW;
    const float4* nbase =
        (const float4*)(noise + ((size_t)b * NS + s0) * DD);
    float4 va[8], vb[8];
    LOADN(va, 0)                               // in flight during coarse phase

    // ---- zero LDS ----
    const uint4 z = make_uint4(0u, 0u, 0u, 0u);
    uint4* c4 = (uint4*)counts;
    c4[tid] = z; c4[tid + 256] = z;
    ((uint4*)hist)[tid] = z;
    #pragma unroll
    for (int i = 0; i < PSEGW; ++i) coarse[tid * PSEGW + i] = 0u;
    if (tid < WPB) candCnt[tid] = 0u;
    __syncthreads();                            // B0: zeros visible

    // ---- block coarse histogram of x (all 4 waves add: counts x4) ----
    CRS4(0) CRS4(1) CRS4(2) CRS4(3) CRS4(4) CRS4(5) CRS4(6) CRS4(7)
    __syncthreads();                            // B1

    // ---- block suffix-scan over 4096 coarse bins, crossing at KK4 ----
    {
        uint32_t h[16], seg = 0;
        #pragma unroll
        for (int i = 0; i < 16; ++i) { h[i] = coarse[tid * PSEGW + i]; seg += h[i]; }
        uint32_t sfx = seg;
        #pragma unroll
        for (int st = 1; st < 64; st <<= 1) {
            uint32_t o = __shfl_down(sfx, (unsigned)st, 64);
            if (lane + st < 64) sfx += o;
        }
        if (lane == 0) wsum[wid] = sfx;
        __syncthreads();                        // B2
        uint32_t hi = 0;
        #pragma unroll
        for (int w = 0; w < 4; ++w) if (w > wid) hi += wsum[w];
        const uint32_t incl  = sfx + hi;
        const uint32_t above = incl - seg;
        if (above < KK4 && incl >= KK4) {
            uint32_t c = above;
            #pragma unroll
            for (int i = 15; i >= 0; --i) {
                if (c + h[i] >= KK4) {
                    sh_lo = inv_orderable(((uint32_t)(tid * 16 + i)) << 20) - WHALF;
                    break;
                }
                c += h[i];
            }
        }
    }
    __syncthreads();                            // B3
    const float lo = sh_lo;

    uint32_t* myHist = hist + wid * NBIN;
    float*    myCf   = cand_f + wid * CWAVE;
    uint32_t* myCd   = cand_d + wid * CWAVE;

    uint32_t cnt0 = 0, cnt1 = 0, cnt2 = 0, cnt3 = 0,
             cnt4 = 0, cnt5 = 0, cnt6 = 0, cnt7 = 0;

    // ---- 2-deep A/B pipeline over SPW=4 samples ----
    LOADN(vb, 1)                 // covered by DO_SAMPLE(va)
    DO_SAMPLE(va)
    LOADN(va, 2)                 // covered by DO_SAMPLE(vb)
    DO_SAMPLE(vb)
    LOADN(vb, 3)                 // covered by DO_SAMPLE(va)
    DO_SAMPLE(va)
    DO_SAMPLE(vb)

    // ---- flush per-wave register counts to block counts ----
    FLUSH4(0) FLUSH4(1) FLUSH4(2) FLUSH4(3)
    FLUSH4(4) FLUSH4(5) FLUSH4(6) FLUSH4(7)
    __syncthreads();                            // all waves' adds landed

    // ---- write group partial counts ----
    if (USE_WS) {
        uint32_t* w32 = (uint32_t*)(ws + ((size_t)b * NG + g) * DD);
        #pragma unroll
        for (int q = 0; q < 2; ++q) {
            uint32_t p = 0;
            #pragma unroll
            for (int e = 0; e < 4; ++e)
                p |= (counts[tid * 8 + q * 4 + e] & 0xFFu) << (8 * e);
            w32[tid * 2 + q] = p;
        }
    } else {
        float* rowOut = outCounts + (size_t)b * DD;
        #pragma unroll
        for (int e = 0; e < 8; ++e) {
            uint32_t c = counts[tid * 8 + e];
            if (c) atomicAdd(&rowOut[tid * 8 + e], (float)c);
        }
    }
}

// Sum NG u8 partials per (b,d), normalize, write both output halves.
__global__ __launch_bounds__(256) void reduce_kernel(
    const unsigned char* __restrict__ ws, float* __restrict__ out)
{
    int idx = blockIdx.x * 256 + threadIdx.x;  // 0 .. BB*DD/4-1
    int b   = idx / (DD / 4);
    int dq  = idx - b * (DD / 4);
    const unsigned char* base = ws + (size_t)b * NG * DD + (size_t)dq * 4;
    uint32_t s0 = 0, s1 = 0, s2 = 0, s3 = 0;
    #pragma unroll
    for (int g = 0; g < NG; ++g) {
        uint32_t p = *(const uint32_t*)(base + (size_t)g * DD);
        s0 += p & 0xFFu; s1 += (p >> 8) & 0xFFu;
        s2 += (p >> 16) & 0xFFu; s3 += (p >> 24) & 0xFFu;
    }
    const float inv = 1.0f / 256.0f;
    float4 t = make_float4(s0 * inv, s1 * inv, s2 * inv, s3 * inv);
    *(float4*)(out + (size_t)b * DD + dq * 4) = t;
    *(float4*)(out + (size_t)(BB * DD) + (size_t)b * DD + dq * 4) =
        make_float4(1.0f - t.x, 1.0f - t.y, 1.0f - t.z, 1.0f - t.w);
}

// Fallback finalize (only when ws is too small): counts -> (topk, 1-topk).
__global__ __launch_bounds__(256) void finalize_kernel(float* __restrict__ out) {
    int i = blockIdx.x * 256 + threadIdx.x;  // 0 .. BB*DD-1
    float t = out[i] * (1.0f / 256.0f);
    out[i] = t;
    out[BB * DD + i] = 1.0f - t;
}

extern "C" void kernel_launch(void* const* d_in, const int* in_sizes, int n_in,
                              void* d_out, int out_size, void* d_ws, size_t ws_size,
                              hipStream_t stream) {
    const float* x     = (const float*)d_in[0];
    const float* noise = (const float*)d_in[1];
    float* out = (float*)d_out;

    const size_t partials = (size_t)BB * NG * DD;           // 2 MB of u8
    if (ws_size >= partials) {
        unsigned char* ws8 = (unsigned char*)d_ws;
        topk_fused_kernel<1><<<BB * NG, 256, 0, stream>>>(x, noise, ws8, nullptr);
        reduce_kernel<<<(BB * DD / 4) / 256, 256, 0, stream>>>(ws8, out);
    } else {
        hipMemsetAsync(out, 0, (size_t)BB * DD * sizeof(float), stream);
        topk_fused_kernel<0><<<BB * NG, 256, 0, stream>>>(x, noise, nullptr, out);
        finalize_kernel<<<(BB * DD) / 256, 256, 0, stream>>>(out);
    }
}

// Round 9
// 50.839 us; speedup vs baseline: 1.1367x; 1.1367x over previous
//
#include <hip/hip_runtime.h>

#define DD    2048
#define KK    256
#define NS    256
#define BB    64
#define SPW   2              // samples per wave
#define WPB   4              // waves per block
#define SPB   (SPW * WPB)    // 8 samples per block
#define NG    (NS / SPB)     // 32 groups (blocks) per b
#define NBIN  256            // fine-window bins
#define WHALF 0.5f           // window half-width around tEst
#define FSCALE 256.0f        // NBIN / (2*WHALF)
#define CWAVE 32             // candidate slots per wave
#define PSEGW 17             // thresh kernel: padded coarse segments

// Map float bits to order-preserving unsigned, and back.
__device__ __forceinline__ uint32_t orderable(float f) {
    uint32_t u = __float_as_uint(f);
    return (u & 0x80000000u) ? ~u : (u | 0x80000000u);
}
__device__ __forceinline__ float inv_orderable(uint32_t u) {
    return (u & 0x80000000u) ? __uint_as_float(u & 0x7FFFFFFFu)
                             : __uint_as_float(~u);
}

// Per-b approximate top-K threshold of x (lower edge of crossing 12-bit
// bucket; error < 0.125 in the relevant range). One block per b.
__global__ __launch_bounds__(256) void thresh_kernel(
    const float* __restrict__ x, float* __restrict__ tEst)
{
    const int tid  = threadIdx.x;
    const int b    = blockIdx.x;
    const int lane = tid & 63;
    const int wid  = tid >> 6;
    __shared__ uint32_t hist[256 * PSEGW];
    __shared__ uint32_t wsum[4];

    #pragma unroll
    for (int i = 0; i < PSEGW; ++i) hist[tid * PSEGW + i] = 0u;
    __syncthreads();

    const float4* xr = (const float4*)(x + (size_t)b * DD);
    float4 a0 = xr[tid * 2 + 0], a1 = xr[tid * 2 + 1];
    uint32_t u[8];
    u[0] = orderable(a0.x); u[1] = orderable(a0.y);
    u[2] = orderable(a0.z); u[3] = orderable(a0.w);
    u[4] = orderable(a1.x); u[5] = orderable(a1.y);
    u[6] = orderable(a1.z); u[7] = orderable(a1.w);
    #pragma unroll
    for (int e = 0; e < 8; ++e) {
        uint32_t bkt = u[e] >> 20;
        atomicAdd(&hist[(bkt >> 4) * PSEGW + (bkt & 15u)], 1u);
    }
    __syncthreads();

    uint32_t h[16], seg = 0;
    #pragma unroll
    for (int i = 0; i < 16; ++i) { h[i] = hist[tid * PSEGW + i]; seg += h[i]; }
    uint32_t sfx = seg;
    #pragma unroll
    for (int st = 1; st < 64; st <<= 1) {
        uint32_t o = __shfl_down(sfx, (unsigned)st, 64);
        if (lane + st < 64) sfx += o;
    }
    if (lane == 0) wsum[wid] = sfx;
    __syncthreads();
    uint32_t hi = 0;
    #pragma unroll
    for (int w = 0; w < 4; ++w) if (w > wid) hi += wsum[w];
    const uint32_t incl  = sfx + hi;
    const uint32_t above = incl - seg;
    if (above < KK && incl >= KK) {
        uint32_t c = above;
        #pragma unroll
        for (int i = 15; i >= 0; --i) {
            if (c + h[i] >= KK) {
                tEst[b] = inv_orderable(((uint32_t)(tid * 16 + i)) << 20);
                break;
            }
            c += h[i];
        }
    }
}

// ---- macros (explicit components / static indices: no scratch) ----
#define BIN1(Q, COMP)                                                   \
    { float val = v[Q].COMP;                                            \
      if (val >= lo) {                                                  \
          int r = (int)((val - lo) * FSCALE);                           \
          if (r >= NBIN) ++W; else atomicAdd(&myHist[r], 1u);           \
      } }
#define BIN4(Q) BIN1(Q, x) BIN1(Q, y) BIN1(Q, z) BIN1(Q, w)

#define CLS1(Q, J, COMP)                                                \
    { float val = v[Q].COMP;                                            \
      if (val >= lo) {                                                  \
          int r = (int)((val - lo) * FSCALE);                           \
          if (r > tb) {                                                 \
              cnt##Q += (1u << (8 * (J)));   /* register byte ctr */    \
          } else if (r == tb) {                                         \
              uint32_t jj = atomicAdd(&candCnt[wid], 1u);               \
              if (jj < CWAVE) {                                         \
                  myCf[jj] = val;                                       \
                  myCd[jj] = (uint32_t)(((Q) << 8) + lane * 4 + (J));   \
              }                                                         \
          }                                                             \
      } }
#define CLS4(Q) CLS1(Q, 0, x) CLS1(Q, 1, y) CLS1(Q, 2, z) CLS1(Q, 3, w)

#define FLUSH1(Q, J)                                                    \
    { uint32_t byt = (cnt##Q >> (8 * (J))) & 0xFFu;                     \
      if (byt) atomicAdd(&counts[((Q) << 8) + lane * 4 + (J)], byt); }
#define FLUSH4(Q) FLUSH1(Q, 0) FLUSH1(Q, 1) FLUSH1(Q, 2) FLUSH1(Q, 3)

// Wave-per-sample kernel: block = (b, group of SPB samples); wave w handles
// SPW samples wave-synchronously. Short blocks + 2x grid = flow scheduling.
template <int USE_WS>
__global__ __launch_bounds__(256) void topk_wave_kernel(
    const float* __restrict__ x,
    const float* __restrict__ noise,
    const float* __restrict__ tEst,
    unsigned char* __restrict__ ws,      // [BB][NG][DD] u8 partials
    float* __restrict__ outCounts)       // [BB][DD] f32 (fallback, pre-zeroed)
{
    const int tid  = threadIdx.x;
    const int bg   = blockIdx.x;
    const int b    = bg >> 5;            // / NG (NG=32)
    const int g    = bg & (NG - 1);
    const int lane = tid & 63;
    const int wid  = tid >> 6;

    __shared__ uint32_t counts[DD];            // 8 KB
    __shared__ uint32_t hist[WPB * NBIN];      // 4 KB, per-wave fine hist
    __shared__ float    cand_f[WPB * CWAVE];
    __shared__ uint32_t cand_d[WPB * CWAVE];
    __shared__ uint32_t candCnt[WPB];

    // ---- init ----
    const uint4 z = make_uint4(0u, 0u, 0u, 0u);
    uint4* c4 = (uint4*)counts;
    c4[tid] = z; c4[tid + 256] = z;
    ((uint4*)hist)[tid] = z;
    if (tid < WPB) candCnt[tid] = 0u;

    const float lo = tEst[b] - WHALF;

    // ---- x row -> registers: lane's element d = 256q + 4*lane + j ----
    const float4* xr = (const float4*)(x + (size_t)b * DD);
    float4 xv[8];
    #pragma unroll
    for (int q = 0; q < 8; ++q) xv[q] = xr[q * 64 + lane];

    const int s0 = g * SPB + wid * SPW;        // first sample of this wave
    const float4* nbase =
        (const float4*)(noise + ((size_t)b * NS + s0) * DD);

    uint32_t* myHist = hist + wid * NBIN;
    float*    myCf   = cand_f + wid * CWAVE;
    uint32_t* myCd   = cand_d + wid * CWAVE;

    uint32_t cnt0 = 0, cnt1 = 0, cnt2 = 0, cnt3 = 0,
             cnt4 = 0, cnt5 = 0, cnt6 = 0, cnt7 = 0;

    __syncthreads();                            // init visible to all waves

    for (int s = 0; s < SPW; ++s) {
        // ---- load noise, perturb in place ----
        const float4* nr = nbase + (size_t)s * (DD / 4);
        float4 v[8];
        #pragma unroll
        for (int q = 0; q < 8; ++q) v[q] = nr[q * 64 + lane];
        #pragma unroll
        for (int q = 0; q < 8; ++q) {
            v[q].x = fmaf(v[q].x, 0.05f, xv[q].x);
            v[q].y = fmaf(v[q].y, 0.05f, xv[q].y);
            v[q].z = fmaf(v[q].z, 0.05f, xv[q].z);
            v[q].w = fmaf(v[q].w, 0.05f, xv[q].w);
        }

        // ---- bin in-window; count above-window ----
        uint32_t W = 0;
        BIN4(0) BIN4(1) BIN4(2) BIN4(3) BIN4(4) BIN4(5) BIN4(6) BIN4(7)
        #pragma unroll
        for (int st = 32; st >= 1; st >>= 1)
            W += __shfl_down(W, (unsigned)st, 64);
        W = __shfl(W, 0, 64);

        // ---- wave suffix scan over 256 bins (lane owns 4*lane..+3) ----
        uint4 hh = *(const uint4*)&myHist[lane * 4];
        const uint32_t h0 = hh.x, h1 = hh.y, h2 = hh.z, h3 = hh.w;
        uint32_t seg = h0 + h1 + h2 + h3;
        uint32_t sfx = seg;
        #pragma unroll
        for (int st = 1; st < 64; st <<= 1) {
            uint32_t o = __shfl_down(sfx, (unsigned)st, 64);
            if (lane + st < 64) sfx += o;
        }
        const uint32_t incl  = sfx + W;
        const uint32_t above = incl - seg;

        // ---- crossing bin via ballot ----
        bool cross = (above < KK && incl >= KK);
        unsigned long long mask = __ballot(cross);
        int tbl = NBIN + 1; uint32_t Rl = 0;
        if (cross) {
            uint32_t c = above;
            if (c + h3 >= KK)                { tbl = lane * 4 + 3; Rl = KK - c; }
            else if (c + h3 + h2 >= KK)      { tbl = lane * 4 + 2; Rl = KK - c - h3; }
            else if (c + h3 + h2 + h1 >= KK) { tbl = lane * 4 + 1; Rl = KK - c - h3 - h2; }
            else                             { tbl = lane * 4 + 0; Rl = KK - c - h3 - h2 - h1; }
        }
        int srcl = mask ? (__ffsll((long long)mask) - 1) : 0;
        int      tb = __shfl(tbl, srcl, 64);
        uint32_t R  = __shfl(Rl,  srcl, 64);
        if (!mask) { tb = NBIN + 1; R = 0; }

        // ---- classify into register byte counters; candidates -> LDS ----
        CLS4(0) CLS4(1) CLS4(2) CLS4(3) CLS4(4) CLS4(5) CLS4(6) CLS4(7)

        // ---- exact rank-select top R among wave candidates ----
        uint32_t M = candCnt[wid];
        if (M > CWAVE) M = CWAVE;
        for (uint32_t j = lane; j < M; j += 64) {
            float    vv = myCf[j];
            uint32_t dj = myCd[j];
            uint32_t r  = 0;
            for (uint32_t i = 0; i < M; ++i) {
                float vi = myCf[i];
                r += (vi > vv) || (vi == vv && myCd[i] < dj);
            }
            if (r < R) atomicAdd(&counts[dj], 1u);
        }
        if (lane == 0) candCnt[wid] = 0u;
        *(uint4*)&myHist[lane * 4] = z;        // zero own fine bins
    }

    // ---- flush per-wave register counts to block counts ----
    FLUSH4(0) FLUSH4(1) FLUSH4(2) FLUSH4(3)
    FLUSH4(4) FLUSH4(5) FLUSH4(6) FLUSH4(7)
    __syncthreads();                            // all waves' adds landed

    // ---- write group partial counts ----
    if (USE_WS) {
        uint32_t* w32 = (uint32_t*)(ws + ((size_t)b * NG + g) * DD);
        #pragma unroll
        for (int q = 0; q < 2; ++q) {
            uint32_t p = 0;
            #pragma unroll
            for (int e = 0; e < 4; ++e)
                p |= (counts[tid * 8 + q * 4 + e] & 0xFFu) << (8 * e);
            w32[tid * 2 + q] = p;
        }
    } else {
        float* rowOut = outCounts + (size_t)b * DD;
        #pragma unroll
        for (int e = 0; e < 8; ++e) {
            uint32_t c = counts[tid * 8 + e];
            if (c) atomicAdd(&rowOut[tid * 8 + e], (float)c);
        }
    }
}

// Sum NG u8 partials per (b,d), normalize, write both output halves.
__global__ __launch_bounds__(256) void reduce_kernel(
    const unsigned char* __restrict__ ws, float* __restrict__ out)
{
    int idx = blockIdx.x * 256 + threadIdx.x;  // 0 .. BB*DD/4-1
    int b   = idx / (DD / 4);
    int dq  = idx - b * (DD / 4);
    const unsigned char* base = ws + (size_t)b * NG * DD + (size_t)dq * 4;
    uint32_t s0 = 0, s1 = 0, s2 = 0, s3 = 0;
    #pragma unroll
    for (int g = 0; g < NG; ++g) {
        uint32_t p = *(const uint32_t*)(base + (size_t)g * DD);
        s0 += p & 0xFFu; s1 += (p >> 8) & 0xFFu;
        s2 += (p >> 16) & 0xFFu; s3 += (p >> 24) & 0xFFu;
    }
    const float inv = 1.0f / 256.0f;
    float4 t = make_float4(s0 * inv, s1 * inv, s2 * inv, s3 * inv);
    *(float4*)(out + (size_t)b * DD + dq * 4) = t;
    *(float4*)(out + (size_t)(BB * DD) + (size_t)b * DD + dq * 4) =
        make_float4(1.0f - t.x, 1.0f - t.y, 1.0f - t.z, 1.0f - t.w);
}

// Fallback finalize (only when ws is too small): counts -> (topk, 1-topk).
__global__ __launch_bounds__(256) void finalize_kernel(float* __restrict__ out) {
    int i = blockIdx.x * 256 + threadIdx.x;  // 0 .. BB*DD-1
    float t = out[i] * (1.0f / 256.0f);
    out[i] = t;
    out[BB * DD + i] = 1.0f - t;
}

extern "C" void kernel_launch(void* const* d_in, const int* in_sizes, int n_in,
                              void* d_out, int out_size, void* d_ws, size_t ws_size,
                              hipStream_t stream) {
    const float* x     = (const float*)d_in[0];
    const float* noise = (const float*)d_in[1];
    float* out = (float*)d_out;

    const size_t partials = (size_t)BB * NG * DD;           // 4 MB of u8
    if (ws_size >= partials + BB * sizeof(float)) {
        unsigned char* ws8 = (unsigned char*)d_ws;
        float* tEst = (float*)(ws8 + partials);
        thresh_kernel<<<BB, 256, 0, stream>>>(x, tEst);
        topk_wave_kernel<1><<<BB * NG, 256, 0, stream>>>(x, noise, tEst, ws8, nullptr);
        reduce_kernel<<<(BB * DD / 4) / 256, 256, 0, stream>>>(ws8, out);
    } else {
        float* tEst = (float*)d_ws;                         // needs 256 B
        hipMemsetAsync(out, 0, (size_t)BB * DD * sizeof(float), stream);
        thresh_kernel<<<BB, 256, 0, stream>>>(x, tEst);
        topk_wave_kernel<0><<<BB * NG, 256, 0, stream>>>(x, noise, tEst, nullptr, out);
        finalize_kernel<<<(BB * DD) / 256, 256, 0, stream>>>(out);
    }
}